// Round 1
// baseline (1461.968 us; speedup 1.0000x reference)
//
#include <hip/hip_runtime.h>
#include <hip/hip_bf16.h>
#include <stdint.h>
#include <type_traits>

#define DEV __device__ __forceinline__

typedef __attribute__((ext_vector_type(8))) short short8;
typedef __attribute__((ext_vector_type(4))) float floatx4;

DEV unsigned short f2bf(float f) {
  union { float f; uint32_t u; } v; v.f = f;
  uint32_t u = v.u;
  u += 0x7fffu + ((u >> 16) & 1u);   // RNE
  return (unsigned short)(u >> 16);
}
DEV float bf2f(unsigned short s) {
  union { uint32_t u; float f; } v; v.u = ((uint32_t)s) << 16;
  return v.f;
}
DEV float rlane(float v, int lane) {
  return __int_as_float(__builtin_amdgcn_readlane(__float_as_int(v), lane));
}

// ---------------------------------------------------------------------------
// Tiled bf16 MFMA GEMM: C[M,N] = A[M,K] * Bw[K,N] + bias[N]
// Block: 256 thr (4 waves, 2x2), tile 128x128, BK=32.
// EPI==0: scatter qkv (bf16) to q/k/v workspace (K transposed [bh][d][T]).
// EPI==1: store fp32 to out.
// ---------------------------------------------------------------------------
template <int EPI, typename TA>
__global__ __launch_bounds__(256)
void gemm_bias_kernel(const TA* __restrict__ A, const float* __restrict__ Bw,
                      const float* __restrict__ bias, int M, int N, int K,
                      unsigned short* __restrict__ qws,
                      unsigned short* __restrict__ kws,
                      unsigned short* __restrict__ vws,
                      float* __restrict__ out) {
  constexpr int LDP = 40;  // LDS row pitch in bf16 (80B: 16B-aligned, breaks conflicts)
  __shared__ __align__(16) unsigned short As[128 * LDP];
  __shared__ __align__(16) unsigned short Bs[128 * LDP];
  const int tid = threadIdx.x;
  const int wid = tid >> 6, lane = tid & 63;
  const int quad = lane >> 4, l16 = lane & 15;
  const int wm = wid >> 1, wn = wid & 1;
  const int rowA0 = blockIdx.y * 128;
  const int colB0 = blockIdx.x * 128;

  floatx4 acc[4][4];
#pragma unroll
  for (int i = 0; i < 4; ++i)
#pragma unroll
    for (int j = 0; j < 4; ++j) acc[i][j] = (floatx4){0.f, 0.f, 0.f, 0.f};

  for (int kt = 0; kt < K; kt += 32) {
    __syncthreads();
#pragma unroll
    for (int it = 0; it < 4; ++it) {
      const int e = it * 1024 + tid * 4;
      {  // A tile: 128 rows x 32 k, row-major in LDS
        const int m = e >> 5, k = e & 31;
        if constexpr (std::is_same<TA, float>::value) {
          const float4 f = *(const float4*)(A + (size_t)(rowA0 + m) * K + kt + k);
          ushort4 w;
          w.x = f2bf(f.x); w.y = f2bf(f.y); w.z = f2bf(f.z); w.w = f2bf(f.w);
          *(ushort4*)&As[m * LDP + k] = w;
        } else {
          *(ushort4*)&As[m * LDP + k] =
              *(const ushort4*)(A + (size_t)(rowA0 + m) * K + kt + k);
        }
      }
      {  // B tile: stored transposed Bs[n][k]
        const int k = e >> 7, n = e & 127;
        const float4 g = *(const float4*)(Bw + (size_t)(kt + k) * N + colB0 + n);
        Bs[(n + 0) * LDP + k] = f2bf(g.x);
        Bs[(n + 1) * LDP + k] = f2bf(g.y);
        Bs[(n + 2) * LDP + k] = f2bf(g.z);
        Bs[(n + 3) * LDP + k] = f2bf(g.w);
      }
    }
    __syncthreads();

    short8 af[4], bf[4];
#pragma unroll
    for (int i = 0; i < 4; ++i) {
      af[i] = *(const short8*)&As[(wm * 64 + i * 16 + l16) * LDP + quad * 8];
      bf[i] = *(const short8*)&Bs[(wn * 64 + i * 16 + l16) * LDP + quad * 8];
    }
#pragma unroll
    for (int i = 0; i < 4; ++i)
#pragma unroll
      for (int j = 0; j < 4; ++j)
        acc[i][j] =
            __builtin_amdgcn_mfma_f32_16x16x32_bf16(af[i], bf[j], acc[i][j], 0, 0, 0);
  }

  // Epilogue. C/D layout (verified): row = quad*4 + reg, col = lane&15.
#pragma unroll
  for (int i = 0; i < 4; ++i) {
#pragma unroll
    for (int j = 0; j < 4; ++j) {
      const int row0 = rowA0 + wm * 64 + i * 16 + quad * 4;
      const int col = colB0 + wn * 64 + j * 16 + l16;
      const float bv = bias[col];
#pragma unroll
      for (int r = 0; r < 4; ++r) {
        const float v = acc[i][j][r] + bv;
        const int R = row0 + r;
        if constexpr (EPI == 0) {
          const int b = R >> 11, t = R & 2047;
          const int which = col >> 10, c = col & 1023;
          const int h = c >> 6, dd = c & 63;
          const unsigned short bw = f2bf(v);
          const size_t bh = (size_t)(b * 16 + h);
          if (which == 0)      qws[(bh * 2048 + t) * 64 + dd] = bw;       // Q [bh][t][d]
          else if (which == 1) kws[(bh * 64 + dd) * 2048 + t] = bw;       // K [bh][d][t]
          else                 vws[(bh * 2048 + t) * 64 + dd] = bw;       // V [bh][t][d]
        } else {
          out[(size_t)R * N + col] = v;
        }
      }
    }
  }
}

// ---------------------------------------------------------------------------
// Vector flash attention. Grid: (B*H, T/16). Block: 256 thr = 4 waves.
// Each wave owns 4 query rows; K/V chunks of 64 keys staged fp32 in LDS.
// Broadcasts of q and p done via v_readlane (VALU), not LDS.
// ---------------------------------------------------------------------------
__global__ __launch_bounds__(256)
void attn_kernel(const unsigned short* __restrict__ qws,
                 const unsigned short* __restrict__ kws,
                 const unsigned short* __restrict__ vws,
                 unsigned short* __restrict__ yws) {
  constexpr int T = 2048, D = 64;
  __shared__ float Ks[64][64];  // [d][key]
  __shared__ float Vs[64][64];  // [key][d]
  const int tid = threadIdx.x;
  const int wid = tid >> 6, lane = tid & 63;
  const int bh = blockIdx.x;
  const int qbase = blockIdx.y * 16;
  const unsigned short* Q = qws + (size_t)bh * T * D;   // [t][d]
  const unsigned short* Kt = kws + (size_t)bh * D * T;  // [d][t]
  const unsigned short* V = vws + (size_t)bh * T * D;   // [t][d]

  float qreg[4], m[4], l[4], o[4];
  int qg[4];
#pragma unroll
  for (int r = 0; r < 4; ++r) {
    qg[r] = qbase + wid * 4 + r;
    qreg[r] = bf2f(Q[(size_t)qg[r] * D + lane]) * 0.125f;  // fold 1/sqrt(64)
    m[r] = -1e30f; l[r] = 0.f; o[r] = 0.f;
  }

  const int kmax = qbase + 16;
  for (int kb = 0; kb < kmax; kb += 64) {
    __syncthreads();
#pragma unroll
    for (int it = 0; it < 4; ++it) {
      const int e = it * 1024 + tid * 4;
      const int row = e >> 6, c = e & 63;
      {
        const ushort4 u = *(const ushort4*)(Kt + (size_t)row * T + kb + c);
        float4 f;
        f.x = bf2f(u.x); f.y = bf2f(u.y); f.z = bf2f(u.z); f.w = bf2f(u.w);
        *(float4*)&Ks[row][c] = f;
      }
      {
        const ushort4 u = *(const ushort4*)(V + (size_t)(kb + row) * D + c);
        float4 f;
        f.x = bf2f(u.x); f.y = bf2f(u.y); f.z = bf2f(u.z); f.w = bf2f(u.w);
        *(float4*)&Vs[row][c] = f;
      }
    }
    __syncthreads();

    // scores: lane = key index within chunk
    float s[4] = {0.f, 0.f, 0.f, 0.f};
#pragma unroll
    for (int t = 0; t < 64; ++t) {
      const float kv = Ks[t][lane];
#pragma unroll
      for (int r = 0; r < 4; ++r) s[r] += rlane(qreg[r], t) * kv;
    }
    const int kidx = kb + lane;
    float p[4];
#pragma unroll
    for (int r = 0; r < 4; ++r) {
      if (kidx > qg[r]) s[r] = -1e30f;  // causal mask
      float red = s[r];
#pragma unroll
      for (int off = 32; off > 0; off >>= 1)
        red = fmaxf(red, __shfl_xor(red, off, 64));
      const float mn = fmaxf(m[r], red);
      const float alpha = __expf(m[r] - mn);
      p[r] = __expf(s[r] - mn);
      m[r] = mn;
      float ssum = p[r];
#pragma unroll
      for (int off = 32; off > 0; off >>= 1) ssum += __shfl_xor(ssum, off, 64);
      l[r] = l[r] * alpha + ssum;
      o[r] *= alpha;
    }
    // accumulate o[d=lane] += p[j] * V[j][d]
#pragma unroll
    for (int j = 0; j < 64; ++j) {
      const float vv = Vs[j][lane];
#pragma unroll
      for (int r = 0; r < 4; ++r) o[r] += rlane(p[r], j) * vv;
    }
  }

  const int b = bh >> 4, h = bh & 15;
#pragma unroll
  for (int r = 0; r < 4; ++r) {
    yws[((size_t)(b * 2048 + qg[r])) * 1024 + h * 64 + lane] = f2bf(o[r] / l[r]);
  }
}

// ---------------------------------------------------------------------------
extern "C" void kernel_launch(void* const* d_in, const int* in_sizes, int n_in,
                              void* d_out, int out_size, void* d_ws, size_t ws_size,
                              hipStream_t stream) {
  (void)in_sizes; (void)n_in; (void)out_size;
  const float* x = (const float*)d_in[0];
  const float* attn_w = (const float*)d_in[1];
  const float* attn_b = (const float*)d_in[2];
  const float* proj_w = (const float*)d_in[3];
  const float* proj_b = (const float*)d_in[4];
  float* out = (float*)d_out;

  // Workspace layout (bf16): q/k/v [64][2048][64] each, y [8192][1024]
  const size_t NQ = 8388608;  // 4*16*2048*64
  unsigned short* qws = (unsigned short*)d_ws;
  unsigned short* kws = qws + NQ;
  unsigned short* vws = kws + NQ;
  unsigned short* yws = vws + NQ;
  if (ws_size < 4 * NQ * sizeof(unsigned short)) return;  // need 64 MiB

  gemm_bias_kernel<0, float><<<dim3(24, 64), dim3(256), 0, stream>>>(
      x, attn_w, attn_b, 8192, 3072, 1024, qws, kws, vws, nullptr);
  attn_kernel<<<dim3(64, 128), dim3(256), 0, stream>>>(qws, kws, vws, yws);
  gemm_bias_kernel<1, unsigned short><<<dim3(8, 64), dim3(256), 0, stream>>>(
      yws, proj_w, proj_b, 8192, 1024, 1024, nullptr, nullptr, nullptr, out);
}

// Round 3
// 482.425 us; speedup vs baseline: 3.0305x; 3.0305x over previous
//
#include <hip/hip_runtime.h>
#include <hip/hip_bf16.h>
#include <stdint.h>
#include <type_traits>

#define DEV __device__ __forceinline__

typedef __attribute__((ext_vector_type(8))) short short8;
typedef __attribute__((ext_vector_type(8))) _Float16 half8;
typedef __attribute__((ext_vector_type(2))) __fp16 fp16x2;
typedef __attribute__((ext_vector_type(4))) float floatx4;
typedef __attribute__((ext_vector_type(16))) float floatx16;

DEV unsigned short f2bf(float f) {
  union { float f; uint32_t u; } v; v.f = f;
  uint32_t u = v.u;
  u += 0x7fffu + ((u >> 16) & 1u);   // RNE
  return (unsigned short)(u >> 16);
}
DEV unsigned short f2h(float f) {
  union { _Float16 h; unsigned short u; } c; c.h = (_Float16)f; return c.u;
}

// ---------------------------------------------------------------------------
// Tiled bf16 MFMA GEMM: C[M,N] = A[M,K] * Bw[K,N] + bias[N]
// Block: 256 thr (4 waves, 2x2), tile 128x128, BK=32.
// EPI==0: scatter qkv: Q bf16 [bh][t][d] (x0.125), K bf16 [bh][t][d],
//         V f16 transposed [bh][d][t].
// EPI==1: store fp32 to out.
// ---------------------------------------------------------------------------
template <int EPI, typename TA>
__global__ __launch_bounds__(256)
void gemm_bias_kernel(const TA* __restrict__ A, const float* __restrict__ Bw,
                      const float* __restrict__ bias, int M, int N, int K,
                      unsigned short* __restrict__ qws,
                      unsigned short* __restrict__ kws,
                      unsigned short* __restrict__ vws,
                      float* __restrict__ out) {
  constexpr int LDP = 40;  // LDS row pitch in bf16
  __shared__ __align__(16) unsigned short As[128 * LDP];
  __shared__ __align__(16) unsigned short Bs[128 * LDP];
  const int tid = threadIdx.x;
  const int wid = tid >> 6, lane = tid & 63;
  const int quad = lane >> 4, l16 = lane & 15;
  const int wm = wid >> 1, wn = wid & 1;
  const int rowA0 = blockIdx.y * 128;
  const int colB0 = blockIdx.x * 128;

  floatx4 acc[4][4];
#pragma unroll
  for (int i = 0; i < 4; ++i)
#pragma unroll
    for (int j = 0; j < 4; ++j) acc[i][j] = (floatx4){0.f, 0.f, 0.f, 0.f};

  for (int kt = 0; kt < K; kt += 32) {
    __syncthreads();
#pragma unroll
    for (int it = 0; it < 4; ++it) {
      const int e = it * 1024 + tid * 4;
      {  // A tile: 128 rows x 32 k
        const int m = e >> 5, k = e & 31;
        if constexpr (std::is_same<TA, float>::value) {
          const float4 f = *(const float4*)(A + (size_t)(rowA0 + m) * K + kt + k);
          ushort4 w;
          w.x = f2bf(f.x); w.y = f2bf(f.y); w.z = f2bf(f.z); w.w = f2bf(f.w);
          *(ushort4*)&As[m * LDP + k] = w;
        } else {
          *(ushort4*)&As[m * LDP + k] =
              *(const ushort4*)(A + (size_t)(rowA0 + m) * K + kt + k);
        }
      }
      {  // B tile: stored transposed Bs[n][k]
        const int k = e >> 7, n = e & 127;
        const float4 g = *(const float4*)(Bw + (size_t)(kt + k) * N + colB0 + n);
        Bs[(n + 0) * LDP + k] = f2bf(g.x);
        Bs[(n + 1) * LDP + k] = f2bf(g.y);
        Bs[(n + 2) * LDP + k] = f2bf(g.z);
        Bs[(n + 3) * LDP + k] = f2bf(g.w);
      }
    }
    __syncthreads();

    short8 af[4], bfr[4];
#pragma unroll
    for (int i = 0; i < 4; ++i) {
      af[i] = *(const short8*)&As[(wm * 64 + i * 16 + l16) * LDP + quad * 8];
      bfr[i] = *(const short8*)&Bs[(wn * 64 + i * 16 + l16) * LDP + quad * 8];
    }
#pragma unroll
    for (int i = 0; i < 4; ++i)
#pragma unroll
      for (int j = 0; j < 4; ++j)
        acc[i][j] =
            __builtin_amdgcn_mfma_f32_16x16x32_bf16(af[i], bfr[j], acc[i][j], 0, 0, 0);
  }

  // Epilogue. C/D layout: row = quad*4 + reg, col = lane&15.
#pragma unroll
  for (int i = 0; i < 4; ++i) {
#pragma unroll
    for (int j = 0; j < 4; ++j) {
      const int row0 = rowA0 + wm * 64 + i * 16 + quad * 4;
      const int col = colB0 + wn * 64 + j * 16 + l16;
      const float bv = bias[col];
#pragma unroll
      for (int r = 0; r < 4; ++r) {
        const float v = acc[i][j][r] + bv;
        const int R = row0 + r;
        if constexpr (EPI == 0) {
          const int b = R >> 11, t = R & 2047;
          const int which = col >> 10, c = col & 1023;
          const int h = c >> 6, dd = c & 63;
          const size_t bh = (size_t)(b * 16 + h);
          if (which == 0)
            qws[(bh * 2048 + t) * 64 + dd] = f2bf(v * 0.125f);  // Q, scale folded
          else if (which == 1)
            kws[(bh * 2048 + t) * 64 + dd] = f2bf(v);           // K [bh][t][d]
          else
            vws[(bh * 64 + dd) * 2048 + t] = f2h(v);            // V^T f16 [bh][d][t]
        } else {
          out[(size_t)R * N + col] = v;
        }
      }
    }
  }
}

// ---------------------------------------------------------------------------
// MFMA flash attention. Grid (64 bh, 16 qtiles), block 256 = 4 waves.
// Computes S^T = K*Q^T (bf16 mfma 32x32x16), online softmax per lane-column,
// then O^T = V^T*P^T (f16 mfma) with register-swap P transpose (no LDS P).
// ---------------------------------------------------------------------------
__global__ __launch_bounds__(256, 2)
void attn_mfma_kernel(const unsigned short* __restrict__ qws,
                      const unsigned short* __restrict__ kws,
                      const unsigned short* __restrict__ vws,
                      unsigned short* __restrict__ yws) {
  constexpr int T = 2048, D = 64;
  __shared__ __align__(16) unsigned short Ks[128 * 72];   // [key][d], pitch 72
  __shared__ __align__(16) unsigned short Vs[64 * 136];   // [d][key], pitch 136
  const int tid = threadIdx.x;
  const int wid = tid >> 6, lane = tid & 63;
  const int hf = lane >> 5, l32 = lane & 31;
  const int bh = blockIdx.x;
  const int qt = 15 - (int)blockIdx.y;  // heavy tiles first
  const int qbase = qt * 128;
  const unsigned short* Qp = qws + (size_t)bh * T * D;
  const unsigned short* Kp = kws + (size_t)bh * T * D;
  const unsigned short* Vp = vws + (size_t)bh * D * T;

  const int q = qbase + wid * 32 + l32;  // this lane's query row
  short8 qf[4];
#pragma unroll
  for (int s = 0; s < 4; ++s)
    qf[s] = *(const short8*)(Qp + (size_t)q * D + s * 16 + hf * 8);

  floatx16 Oacc[2];
#pragma unroll
  for (int mt2 = 0; mt2 < 2; ++mt2)
#pragma unroll
    for (int i = 0; i < 16; ++i) Oacc[mt2][i] = 0.f;
  float mrun = -1e30f, lrun = 0.f;

  for (int kt = 0; kt <= qt; ++kt) {
    const int kb = kt * 128;
    __syncthreads();
#pragma unroll
    for (int it = 0; it < 4; ++it) {
      const int e = it * 256 + tid;
      {
        const int row = e >> 3, c = (e & 7) * 8;
        *(short8*)&Ks[row * 72 + c] =
            *(const short8*)(Kp + (size_t)(kb + row) * D + c);
      }
      {
        const int row = e >> 4, c = (e & 15) * 8;
        *(short8*)&Vs[row * 136 + c] =
            *(const short8*)(Vp + (size_t)row * T + kb + c);
      }
    }
    __syncthreads();

    const bool diag = (kt == qt);
    const int mtmax = diag ? (wid + 1) : 4;  // wave-uniform

    floatx16 S[4];
#pragma unroll
    for (int mt = 0; mt < 4; ++mt)
      if (mt < mtmax)
#pragma unroll
        for (int i = 0; i < 16; ++i) S[mt][i] = 0.f;

#pragma unroll
    for (int s = 0; s < 4; ++s) {
#pragma unroll
      for (int mt = 0; mt < 4; ++mt)
        if (mt < mtmax) {
          const short8 kf =
              *(const short8*)&Ks[(mt * 32 + l32) * 72 + s * 16 + hf * 8];
          S[mt] = __builtin_amdgcn_mfma_f32_32x32x16_bf16(kf, qf[s], S[mt], 0, 0, 0);
        }
    }

    if (diag) {  // mask keys > q on the diagonal key-tile
#pragma unroll
      for (int mt = 0; mt < 4; ++mt)
        if (mt == wid) {
#pragma unroll
          for (int r = 0; r < 16; ++r) {
            const int intra = (r & 3) + 8 * (r >> 2) + 4 * hf;
            if (intra > l32) S[mt][r] = -1e30f;
          }
        }
    }

    float tmax = -1e30f;
#pragma unroll
    for (int mt = 0; mt < 4; ++mt)
      if (mt < mtmax)
#pragma unroll
        for (int r = 0; r < 16; ++r) tmax = fmaxf(tmax, S[mt][r]);
    tmax = fmaxf(tmax, __shfl_xor(tmax, 32, 64));
    const float mn = fmaxf(mrun, tmax);
    const float alpha = __expf(mrun - mn);
    mrun = mn;

    float tsum = 0.f;
    uint32_t pk[4][8];
#pragma unroll
    for (int mt = 0; mt < 4; ++mt)
      if (mt < mtmax)
#pragma unroll
        for (int t = 0; t < 8; ++t) {
          const float pa = __expf(S[mt][2 * t] - mn);
          const float pb = __expf(S[mt][2 * t + 1] - mn);
          tsum += pa + pb;
          union { fp16x2 h; uint32_t u; } cv;
          cv.h = __builtin_amdgcn_cvt_pkrtz(pa, pb);
          pk[mt][t] = cv.u;
        }
    tsum += __shfl_xor(tsum, 32, 64);
    lrun = lrun * alpha + tsum;
#pragma unroll
    for (int mt2 = 0; mt2 < 2; ++mt2)
#pragma unroll
      for (int i = 0; i < 16; ++i) Oacc[mt2][i] *= alpha;

    const int smax = 2 * mtmax;
#pragma unroll
    for (int s = 0; s < 8; ++s)
      if (s < smax) {
        const int mt = s >> 1;
        const int bo = 4 * (s & 1);
        // B-frag regs for this k-step: regs {bo+2h, bo+2h+1} of lanes q, q+32.
        const uint32_t own0 = hf ? pk[mt][bo + 2] : pk[mt][bo];
        const uint32_t own1 = hf ? pk[mt][bo + 3] : pk[mt][bo + 1];
        const uint32_t sendA = hf ? pk[mt][bo] : pk[mt][bo + 2];
        const uint32_t sendB = hf ? pk[mt][bo + 1] : pk[mt][bo + 3];
        const uint32_t recvA = (uint32_t)__shfl_xor((int)sendA, 32, 64);
        const uint32_t recvB = (uint32_t)__shfl_xor((int)sendB, 32, 64);
        union { uint32_t u[4]; half8 h; } bb;
        bb.u[0] = hf ? recvA : own0;
        bb.u[1] = hf ? recvB : own1;
        bb.u[2] = hf ? own0 : recvA;
        bb.u[3] = hf ? own1 : recvB;
#pragma unroll
        for (int mt2 = 0; mt2 < 2; ++mt2) {
          const half8 vf =
              *(const half8*)&Vs[(mt2 * 32 + l32) * 136 + s * 16 + hf * 8];
          Oacc[mt2] = __builtin_amdgcn_mfma_f32_32x32x16_f16(vf, bb.h, Oacc[mt2], 0, 0, 0);
        }
      }
  }

  // Epilogue: O^T C-layout -> y[b][t][h*64+d] bf16. d = mt2*32+2(t&1)+8(t>>1)+4hf.
  const float invl = 1.0f / lrun;
  const int b_ = bh >> 4, h_ = bh & 15;
  unsigned short* yrow = yws + ((size_t)(b_ * 2048 + q)) * 1024 + h_ * 64;
#pragma unroll
  for (int mt2 = 0; mt2 < 2; ++mt2)
#pragma unroll
    for (int t = 0; t < 8; ++t) {
      const int d0 = mt2 * 32 + 2 * (t & 1) + 8 * (t >> 1) + 4 * hf;
      const uint32_t ua = f2bf(Oacc[mt2][2 * t] * invl);
      const uint32_t ub = f2bf(Oacc[mt2][2 * t + 1] * invl);
      *(uint32_t*)&yrow[d0] = ua | (ub << 16);
    }
}

// ---------------------------------------------------------------------------
extern "C" void kernel_launch(void* const* d_in, const int* in_sizes, int n_in,
                              void* d_out, int out_size, void* d_ws, size_t ws_size,
                              hipStream_t stream) {
  (void)in_sizes; (void)n_in; (void)out_size;
  const float* x = (const float*)d_in[0];
  const float* attn_w = (const float*)d_in[1];
  const float* attn_b = (const float*)d_in[2];
  const float* proj_w = (const float*)d_in[3];
  const float* proj_b = (const float*)d_in[4];
  float* out = (float*)d_out;

  // Workspace (2B elems): q/k/v [64][2048][64] each, y [8192][1024]
  const size_t NQ = 8388608;  // 4*16*2048*64
  unsigned short* qws = (unsigned short*)d_ws;
  unsigned short* kws = qws + NQ;
  unsigned short* vws = kws + NQ;
  unsigned short* yws = vws + NQ;
  if (ws_size < 4 * NQ * sizeof(unsigned short)) return;  // need 64 MiB

  gemm_bias_kernel<0, float><<<dim3(24, 64), dim3(256), 0, stream>>>(
      x, attn_w, attn_b, 8192, 3072, 1024, qws, kws, vws, nullptr);
  attn_mfma_kernel<<<dim3(64, 16), dim3(256), 0, stream>>>(qws, kws, vws, yws);
  gemm_bias_kernel<1, unsigned short><<<dim3(8, 64), dim3(256), 0, stream>>>(
      yws, proj_w, proj_b, 8192, 1024, 1024, nullptr, nullptr, nullptr, out);
}

// Round 4
// 282.887 us; speedup vs baseline: 5.1680x; 1.7054x over previous
//
#include <hip/hip_runtime.h>
#include <hip/hip_bf16.h>
#include <stdint.h>

#define DEV __device__ __forceinline__

typedef __attribute__((ext_vector_type(8))) short short8;
typedef __attribute__((ext_vector_type(8))) _Float16 half8;
typedef __attribute__((ext_vector_type(2))) __fp16 fp16x2;
typedef __attribute__((ext_vector_type(4))) float floatx4;
typedef __attribute__((ext_vector_type(16))) float floatx16;

DEV unsigned short f2bf(float f) {
  union { float f; uint32_t u; } v; v.f = f;
  uint32_t u = v.u;
  u += 0x7fffu + ((u >> 16) & 1u);   // RNE
  return (unsigned short)(u >> 16);
}
DEV unsigned short f2h(float f) {
  union { _Float16 h; unsigned short u; } c; c.h = (_Float16)f; return c.u;
}
DEV void async_cp16(const unsigned short* g, unsigned short* l) {
  __builtin_amdgcn_global_load_lds(
      (const __attribute__((address_space(1))) uint32_t*)g,
      (__attribute__((address_space(3))) uint32_t*)l, 16, 0, 0);
}

// ---------------------------------------------------------------------------
// cvt_x: fp32 -> bf16, coalesced. n multiple of 1024.
// ---------------------------------------------------------------------------
__global__ __launch_bounds__(256)
void cvt_x_kernel(const float* __restrict__ x, unsigned short* __restrict__ xb) {
  const size_t i = ((size_t)blockIdx.x * 256 + threadIdx.x) * 4;
  const float4 f = *(const float4*)(x + i);
  ushort4 w;
  w.x = f2bf(f.x); w.y = f2bf(f.y); w.z = f2bf(f.z); w.w = f2bf(f.w);
  *(ushort4*)(xb + i) = w;
}

// ---------------------------------------------------------------------------
// transpose_w: W[K][N] fp32 -> Wt[N][K] bf16. 64x64 LDS tiles.
// Grid (N/64, K/64), block 256.
// ---------------------------------------------------------------------------
__global__ __launch_bounds__(256)
void transpose_w_kernel(const float* __restrict__ W, unsigned short* __restrict__ Wt,
                        int K, int N) {
  __shared__ float tile[64][65];
  const int k0 = blockIdx.y * 64, n0 = blockIdx.x * 64;
  const int tr = threadIdx.x >> 4;          // 0..15
  const int tc = (threadIdx.x & 15) * 4;    // 0..60
#pragma unroll
  for (int it = 0; it < 4; ++it) {
    const int k = tr + it * 16;
    const float4 f = *(const float4*)(W + (size_t)(k0 + k) * N + n0 + tc);
    tile[k][tc + 0] = f.x; tile[k][tc + 1] = f.y;
    tile[k][tc + 2] = f.z; tile[k][tc + 3] = f.w;
  }
  __syncthreads();
#pragma unroll
  for (int it = 0; it < 4; ++it) {
    const int n = tr + it * 16;
    ushort4 w;
    w.x = f2bf(tile[tc + 0][n]); w.y = f2bf(tile[tc + 1][n]);
    w.z = f2bf(tile[tc + 2][n]); w.w = f2bf(tile[tc + 3][n]);
    *(ushort4*)(Wt + (size_t)(n0 + n) * K + k0 + tc) = w;
  }
}

// ---------------------------------------------------------------------------
// m97-structure bf16 GEMM: C[M,N] = A[M,K] * Bt[N,K]^T + bias[N]
// Block 256 (4 waves 2x2), tile 128x128, BK=32, global_load_lds width-16.
// EPI==0: scatter qkv (Q bf16 x0.125 [bh][t][d], K bf16 [bh][t][d],
//         V f16 transposed [bh][d][t]).  EPI==1: fp32 out + bias.
// ---------------------------------------------------------------------------
template <int EPI>
__global__ __launch_bounds__(256)
void gemm_bt_kernel(const unsigned short* __restrict__ A,
                    const unsigned short* __restrict__ Bt,
                    const float* __restrict__ bias, int M, int N, int K,
                    unsigned short* __restrict__ qws,
                    unsigned short* __restrict__ kws,
                    unsigned short* __restrict__ vws,
                    float* __restrict__ out) {
  __shared__ __align__(16) unsigned short As[128 * 32];  // 8 KB, NO padding
  __shared__ __align__(16) unsigned short Bs[128 * 32];  // (global_load_lds)
  const int tid = threadIdx.x;
  const int wid = tid >> 6, lane = tid & 63;
  const int quad = lane >> 4, l16 = lane & 15;
  const int wm = wid >> 1, wn = wid & 1;
  const int rowA0 = blockIdx.y * 128;
  const int colB0 = blockIdx.x * 128;

  // Staging: chunk c (of 512 16B-chunks per tile) covers row c>>2, k=(c&3)*8.
  // Wave w inst j in {0,1}: lane covers chunk w*128 + j*64 + lane.
  const int srow = wid * 32 + (lane >> 2);      // + j*16
  const int sko = (lane & 3) * 8;
  const unsigned short* gA0 = A + (size_t)(rowA0 + srow) * K + sko;
  const unsigned short* gA1 = A + (size_t)(rowA0 + srow + 16) * K + sko;
  const unsigned short* gB0 = Bt + (size_t)(colB0 + srow) * K + sko;
  const unsigned short* gB1 = Bt + (size_t)(colB0 + srow + 16) * K + sko;
  unsigned short* lA0 = &As[(wid * 128 + 0) * 8];   // wave-uniform LDS bases
  unsigned short* lA1 = &As[(wid * 128 + 64) * 8];
  unsigned short* lB0 = &Bs[(wid * 128 + 0) * 8];
  unsigned short* lB1 = &Bs[(wid * 128 + 64) * 8];

  floatx4 acc[4][4];
#pragma unroll
  for (int i = 0; i < 4; ++i)
#pragma unroll
    for (int j = 0; j < 4; ++j) acc[i][j] = (floatx4){0.f, 0.f, 0.f, 0.f};

  for (int kt = 0; kt < K; kt += 32) {
    __syncthreads();
    async_cp16(gA0 + kt, lA0);
    async_cp16(gA1 + kt, lA1);
    async_cp16(gB0 + kt, lB0);
    async_cp16(gB1 + kt, lB1);
    __syncthreads();

    short8 af[4], bfr[4];
#pragma unroll
    for (int i = 0; i < 4; ++i) {
      af[i] = *(const short8*)&As[(wm * 64 + i * 16 + l16) * 32 + quad * 8];
      bfr[i] = *(const short8*)&Bs[(wn * 64 + i * 16 + l16) * 32 + quad * 8];
    }
#pragma unroll
    for (int i = 0; i < 4; ++i)
#pragma unroll
      for (int j = 0; j < 4; ++j)
        acc[i][j] =
            __builtin_amdgcn_mfma_f32_16x16x32_bf16(af[i], bfr[j], acc[i][j], 0, 0, 0);
  }

  // Epilogue. C/D layout: row = quad*4 + reg, col = lane&15.
#pragma unroll
  for (int i = 0; i < 4; ++i) {
#pragma unroll
    for (int j = 0; j < 4; ++j) {
      const int row0 = rowA0 + wm * 64 + i * 16 + quad * 4;
      const int col = colB0 + wn * 64 + j * 16 + l16;
      const float bv = bias[col];
#pragma unroll
      for (int r = 0; r < 4; ++r) {
        const float v = acc[i][j][r] + bv;
        const int R = row0 + r;
        if constexpr (EPI == 0) {
          const int b = R >> 11, t = R & 2047;
          const int which = col >> 10, c = col & 1023;
          const int h = c >> 6, dd = c & 63;
          const size_t bh = (size_t)(b * 16 + h);
          if (which == 0)
            qws[(bh * 2048 + t) * 64 + dd] = f2bf(v * 0.125f);  // Q, scale folded
          else if (which == 1)
            kws[(bh * 2048 + t) * 64 + dd] = f2bf(v);           // K [bh][t][d]
          else
            vws[(bh * 64 + dd) * 2048 + t] = f2h(v);            // V^T f16 [bh][d][t]
        } else {
          out[(size_t)R * N + col] = v;
        }
      }
    }
  }
}

// ---------------------------------------------------------------------------
// MFMA flash attention. Grid (64 bh, 16 qtiles), block 256 = 4 waves.
// S^T = K*Q^T (bf16 mfma 32x32x16), online softmax per lane-column,
// O^T = V^T*P^T (f16 mfma) with register-swap P transpose (no LDS P).
// ---------------------------------------------------------------------------
__global__ __launch_bounds__(256, 2)
void attn_mfma_kernel(const unsigned short* __restrict__ qws,
                      const unsigned short* __restrict__ kws,
                      const unsigned short* __restrict__ vws,
                      unsigned short* __restrict__ yws) {
  constexpr int T = 2048, D = 64;
  __shared__ __align__(16) unsigned short Ks[128 * 72];   // [key][d], pitch 72
  __shared__ __align__(16) unsigned short Vs[64 * 136];   // [d][key], pitch 136
  const int tid = threadIdx.x;
  const int wid = tid >> 6, lane = tid & 63;
  const int hf = lane >> 5, l32 = lane & 31;
  const int bh = blockIdx.x;
  const int qt = 15 - (int)blockIdx.y;  // heavy tiles first
  const int qbase = qt * 128;
  const unsigned short* Qp = qws + (size_t)bh * T * D;
  const unsigned short* Kp = kws + (size_t)bh * T * D;
  const unsigned short* Vp = vws + (size_t)bh * D * T;

  const int q = qbase + wid * 32 + l32;  // this lane's query row
  short8 qf[4];
#pragma unroll
  for (int s = 0; s < 4; ++s)
    qf[s] = *(const short8*)(Qp + (size_t)q * D + s * 16 + hf * 8);

  floatx16 Oacc[2];
#pragma unroll
  for (int mt2 = 0; mt2 < 2; ++mt2)
#pragma unroll
    for (int i = 0; i < 16; ++i) Oacc[mt2][i] = 0.f;
  float mrun = -1e30f, lrun = 0.f;

  for (int kt = 0; kt <= qt; ++kt) {
    const int kb = kt * 128;
    __syncthreads();
#pragma unroll
    for (int it = 0; it < 4; ++it) {
      const int e = it * 256 + tid;
      {
        const int row = e >> 3, c = (e & 7) * 8;
        *(short8*)&Ks[row * 72 + c] =
            *(const short8*)(Kp + (size_t)(kb + row) * D + c);
      }
      {
        const int row = e >> 4, c = (e & 15) * 8;
        *(short8*)&Vs[row * 136 + c] =
            *(const short8*)(Vp + (size_t)row * T + kb + c);
      }
    }
    __syncthreads();

    const bool diag = (kt == qt);
    const int mtmax = diag ? (wid + 1) : 4;  // wave-uniform

    floatx16 S[4];
#pragma unroll
    for (int mt = 0; mt < 4; ++mt)
      if (mt < mtmax)
#pragma unroll
        for (int i = 0; i < 16; ++i) S[mt][i] = 0.f;

#pragma unroll
    for (int s = 0; s < 4; ++s) {
#pragma unroll
      for (int mt = 0; mt < 4; ++mt)
        if (mt < mtmax) {
          const short8 kf =
              *(const short8*)&Ks[(mt * 32 + l32) * 72 + s * 16 + hf * 8];
          S[mt] = __builtin_amdgcn_mfma_f32_32x32x16_bf16(kf, qf[s], S[mt], 0, 0, 0);
        }
    }

    if (diag) {  // mask keys > q on the diagonal key-tile
#pragma unroll
      for (int mt = 0; mt < 4; ++mt)
        if (mt == wid) {
#pragma unroll
          for (int r = 0; r < 16; ++r) {
            const int intra = (r & 3) + 8 * (r >> 2) + 4 * hf;
            if (intra > l32) S[mt][r] = -1e30f;
          }
        }
    }

    float tmax = -1e30f;
#pragma unroll
    for (int mt = 0; mt < 4; ++mt)
      if (mt < mtmax)
#pragma unroll
        for (int r = 0; r < 16; ++r) tmax = fmaxf(tmax, S[mt][r]);
    tmax = fmaxf(tmax, __shfl_xor(tmax, 32, 64));
    const float mn = fmaxf(mrun, tmax);
    const float alpha = __expf(mrun - mn);
    mrun = mn;

    float tsum = 0.f;
    uint32_t pk[4][8];
#pragma unroll
    for (int mt = 0; mt < 4; ++mt)
      if (mt < mtmax)
#pragma unroll
        for (int t = 0; t < 8; ++t) {
          const float pa = __expf(S[mt][2 * t] - mn);
          const float pb = __expf(S[mt][2 * t + 1] - mn);
          tsum += pa + pb;
          union { fp16x2 h; uint32_t u; } cv;
          cv.h = __builtin_amdgcn_cvt_pkrtz(pa, pb);
          pk[mt][t] = cv.u;
        }
    tsum += __shfl_xor(tsum, 32, 64);
    lrun = lrun * alpha + tsum;
#pragma unroll
    for (int mt2 = 0; mt2 < 2; ++mt2)
#pragma unroll
      for (int i = 0; i < 16; ++i) Oacc[mt2][i] *= alpha;

    const int smax = 2 * mtmax;
#pragma unroll
    for (int s = 0; s < 8; ++s)
      if (s < smax) {
        const int mt = s >> 1;
        const int bo = 4 * (s & 1);
        // B-frag regs for this k-step: regs {bo+2h, bo+2h+1} of lanes q, q+32.
        const uint32_t own0 = hf ? pk[mt][bo + 2] : pk[mt][bo];
        const uint32_t own1 = hf ? pk[mt][bo + 3] : pk[mt][bo + 1];
        const uint32_t sendA = hf ? pk[mt][bo] : pk[mt][bo + 2];
        const uint32_t sendB = hf ? pk[mt][bo + 1] : pk[mt][bo + 3];
        const uint32_t recvA = (uint32_t)__shfl_xor((int)sendA, 32, 64);
        const uint32_t recvB = (uint32_t)__shfl_xor((int)sendB, 32, 64);
        union { uint32_t u[4]; half8 h; } bb;
        bb.u[0] = hf ? recvA : own0;
        bb.u[1] = hf ? recvB : own1;
        bb.u[2] = hf ? own0 : recvA;
        bb.u[3] = hf ? own1 : recvB;
#pragma unroll
        for (int mt2 = 0; mt2 < 2; ++mt2) {
          const half8 vf =
              *(const half8*)&Vs[(mt2 * 32 + l32) * 136 + s * 16 + hf * 8];
          Oacc[mt2] = __builtin_amdgcn_mfma_f32_32x32x16_f16(vf, bb.h, Oacc[mt2], 0, 0, 0);
        }
      }
  }

  // Epilogue: O^T C-layout -> y[b][t][h*64+d] bf16. d = mt2*32+2(t&1)+8(t>>1)+4hf.
  const float invl = 1.0f / lrun;
  const int b_ = bh >> 4, h_ = bh & 15;
  unsigned short* yrow = yws + ((size_t)(b_ * 2048 + q)) * 1024 + h_ * 64;
#pragma unroll
  for (int mt2 = 0; mt2 < 2; ++mt2)
#pragma unroll
    for (int t = 0; t < 8; ++t) {
      const int d0 = mt2 * 32 + 2 * (t & 1) + 8 * (t >> 1) + 4 * hf;
      const uint32_t ua = f2bf(Oacc[mt2][2 * t] * invl);
      const uint32_t ub = f2bf(Oacc[mt2][2 * t + 1] * invl);
      *(uint32_t*)&yrow[d0] = ua | (ub << 16);
    }
}

// ---------------------------------------------------------------------------
extern "C" void kernel_launch(void* const* d_in, const int* in_sizes, int n_in,
                              void* d_out, int out_size, void* d_ws, size_t ws_size,
                              hipStream_t stream) {
  (void)in_sizes; (void)n_in; (void)out_size;
  const float* x = (const float*)d_in[0];
  const float* attn_w = (const float*)d_in[1];
  const float* attn_b = (const float*)d_in[2];
  const float* proj_w = (const float*)d_in[3];
  const float* proj_b = (const float*)d_in[4];
  float* out = (float*)d_out;

  // Workspace (2B units): qkv 3x8M, y 8M, xb 8M, wta 3M, wtp 1M  => ~94 MiB
  const size_t NQ = 8388608;  // 4*16*2048*64 == 8192*1024
  unsigned short* qws = (unsigned short*)d_ws;
  unsigned short* kws = qws + NQ;
  unsigned short* vws = kws + NQ;
  unsigned short* yws = vws + NQ;
  unsigned short* xb  = yws + NQ;
  unsigned short* wta = xb + NQ;               // 3072*1024
  unsigned short* wtp = wta + 3072 * 1024;     // 1024*1024
  if (ws_size < (5 * NQ + 4 * 1024 * 1024) * sizeof(unsigned short)) return;

  cvt_x_kernel<<<dim3(8192), dim3(256), 0, stream>>>(x, xb);
  transpose_w_kernel<<<dim3(48, 16), dim3(256), 0, stream>>>(attn_w, wta, 1024, 3072);
  transpose_w_kernel<<<dim3(16, 16), dim3(256), 0, stream>>>(proj_w, wtp, 1024, 1024);

  gemm_bt_kernel<0><<<dim3(24, 64), dim3(256), 0, stream>>>(
      xb, wta, attn_b, 8192, 3072, 1024, qws, kws, vws, nullptr);
  attn_mfma_kernel<<<dim3(64, 16), dim3(256), 0, stream>>>(qws, kws, vws, yws);
  gemm_bt_kernel<1><<<dim3(8, 64), dim3(256), 0, stream>>>(
      yws, wtp, proj_b, 8192, 1024, 1024, nullptr, nullptr, nullptr, out);
}